// Round 7
// baseline (234.349 us; speedup 1.0000x reference)
//
#include <hip/hip_runtime.h>
#include <stdint.h>
#include <math.h>

typedef _Float16 f16;
typedef _Float16 f16x4 __attribute__((ext_vector_type(4)));
typedef _Float16 f16x8 __attribute__((ext_vector_type(8)));
typedef float f32x4 __attribute__((ext_vector_type(4)));
typedef float f32x16 __attribute__((ext_vector_type(16)));
typedef unsigned int u32;

#define D_MODEL 1024
#define N_HEAD 16
#define BATCH 2
#define SEQ 2048
#define MTOT 4096
#define NQKV 3072
// 0.125 * log2(e): folded into Q so sigmoid(x/8) = 1/(1+exp2(-Qs.K))
#define QSCALE 0.18033688011112042f

__device__ __forceinline__ void llds16(const void* g, void* l) {
  __builtin_amdgcn_global_load_lds(
      (const __attribute__((address_space(1))) unsigned int*)g,
      (__attribute__((address_space(3))) unsigned int*)l, 16, 0, 0);
}

__device__ __forceinline__ float fast_rcp(float x) {
#if __has_builtin(__builtin_amdgcn_rcpf)
  return __builtin_amdgcn_rcpf(x);
#else
  return 1.0f / x;
#endif
}

__device__ __forceinline__ float fast_exp2(float x) {
#if __has_builtin(__builtin_amdgcn_exp2f)
  return __builtin_amdgcn_exp2f(x);
#else
  return exp2f(x);
#endif
}

// sigmoid with pre-scaled scores: s already = (Q.K/8)*log2e
#define SIG(s) fast_rcp(1.0f + fast_exp2(-(s)))

__device__ __forceinline__ u32 pk2(float a, float b) {
  auto h = __builtin_amdgcn_cvt_pkrtz(a, b);  // __fp16 ext_vector(2)
  return __builtin_bit_cast(u32, h);
}

// ---- fused fp32->fp16 convert of q,k,v (contiguous 12M-elem dest) ----
__global__ void k_cvt3(const float* __restrict__ q, const float* __restrict__ k,
                       const float* __restrict__ v, f16* __restrict__ dst) {
  const int idx = (blockIdx.x * 256 + threadIdx.x) * 8;
  const int seg = idx >> 22;
  const int off = idx & ((1 << 22) - 1);
  const float* s = (seg == 0) ? q : (seg == 1) ? k : v;
  const float4 a = *(const float4*)(s + off);
  const float4 b = *(const float4*)(s + off + 4);
  f16x8 o;
  o[0] = (f16)a.x; o[1] = (f16)a.y; o[2] = (f16)a.z; o[3] = (f16)a.w;
  o[4] = (f16)b.x; o[5] = (f16)b.y; o[6] = (f16)b.z; o[7] = (f16)b.w;
  *(f16x8*)(dst + idx) = o;
}

// ---- all 4 weights [K][N] fp32 -> [N][K] fp16 in one launch ----
__global__ void k_tw(const float* __restrict__ Wq, const float* __restrict__ Wk,
                     const float* __restrict__ Wv, const float* __restrict__ Wo,
                     f16* __restrict__ WqkvT, f16* __restrict__ WoT) {
  __shared__ float t[32][33];
  const int z = blockIdx.z;
  const float* W = (z == 0) ? Wq : (z == 1) ? Wk : (z == 2) ? Wv : Wo;
  f16* dst = (z < 3) ? (WqkvT + (size_t)z * 1024 * 1024) : WoT;
  const int bx = blockIdx.x * 32, by = blockIdx.y * 32;
  const int tx = threadIdx.x, ty = threadIdx.y;
#pragma unroll
  for (int i = 0; i < 32; i += 8)
    t[ty + i][tx] = W[(size_t)(by + ty + i) * 1024 + bx + tx];
  __syncthreads();
#pragma unroll
  for (int i = 0; i < 32; i += 8)
    dst[(size_t)(bx + ty + i) * 1024 + by + tx] = (f16)t[tx][ty + i];
}

// ---- GEMM: C[4096, Nd]. MODE 0: fused QKV, f16 out; Q-third scaled by QSCALE;
//      V-third written transposed to Vt[(b,h),d,s]. MODE 1: fp32 out. ----
template <int Nd, int MODE>
__global__ __launch_bounds__(512, 4) void k_gemm(const f16* __restrict__ A0,
                                                 const f16* __restrict__ A1,
                                                 const f16* __restrict__ A2,
                                                 const f16* __restrict__ BT,
                                                 const float* __restrict__ b0,
                                                 const float* __restrict__ b1,
                                                 const float* __restrict__ b2,
                                                 void* __restrict__ Cout,
                                                 f16* __restrict__ Vt) {
  constexpr int Kd = 1024;
  constexpr int NBX = Nd / 128;
  constexpr int NWG = (MTOT / 128) * NBX;
  __shared__ __align__(16) f16 As[2][8192];
  __shared__ __align__(16) f16 Bs[2][8192];
  int id = blockIdx.x;
  id = (id & 7) * (NWG / 8) + (id >> 3);
  const int n0 = (id % NBX) * 128, m0 = (id / NBX) * 128;
  const f16* A = (Nd == 1024) ? A0 : (n0 < 1024 ? A0 : n0 < 2048 ? A1 : A2);
  const int tid = threadIdx.x, w = tid >> 6, ln = tid & 63;
  const int wm = w >> 2, wn = w & 3;
  f32x4 acc[4][2] = {};

  auto stage = [&](int buf, int kt) {
    const int k0 = kt * 64;
#pragma unroll
    for (int i = 0; i < 2; ++i) {
      const int c = w * 2 + i;
      const int r = c * 8 + (ln >> 3);
      const int g = ln & 7;
      const int ko = k0 + ((g ^ (r & 7)) * 8);
      llds16(A + (size_t)(m0 + r) * Kd + ko, &As[buf][c * 512]);
      llds16(BT + (size_t)(n0 + r) * Kd + ko, &Bs[buf][c * 512]);
    }
  };
  stage(0, 0);
  __syncthreads();
  int cur = 0;
  for (int kt = 0; kt < Kd / 64; ++kt) {
    if (kt < Kd / 64 - 1) stage(cur ^ 1, kt + 1);
#pragma unroll
    for (int kk = 0; kk < 2; ++kk) {
      f16x8 af[4], bf[2];
#pragma unroll
      for (int mi = 0; mi < 4; ++mi) {
        const int r = wm * 64 + mi * 16 + (ln & 15);
        const int g = kk * 4 + (ln >> 4);
        af[mi] = *(const f16x8*)(&As[cur][r * 64 + ((g ^ (r & 7)) * 8)]);
      }
#pragma unroll
      for (int nf = 0; nf < 2; ++nf) {
        const int r = wn * 32 + nf * 16 + (ln & 15);
        const int g = kk * 4 + (ln >> 4);
        bf[nf] = *(const f16x8*)(&Bs[cur][r * 64 + ((g ^ (r & 7)) * 8)]);
      }
#pragma unroll
      for (int mi = 0; mi < 4; ++mi)
#pragma unroll
        for (int nf = 0; nf < 2; ++nf)
          acc[mi][nf] = __builtin_amdgcn_mfma_f32_16x16x32_f16(af[mi], bf[nf], acc[mi][nf], 0, 0, 0);
    }
    __syncthreads();
    cur ^= 1;
  }
  const float* bb = (Nd == 1024) ? b0 : (n0 < 1024 ? b0 : n0 < 2048 ? b1 : b2);
  const int nb = n0 & 1023;
  if (MODE == 0 && n0 >= 2048) {
    // V third: write transposed into Vt[(b,h), d, s], 8B packed along s
#pragma unroll
    for (int mi = 0; mi < 4; ++mi)
#pragma unroll
      for (int nf = 0; nf < 2; ++nf) {
        const int cl = wn * 32 + nf * 16 + (ln & 15);
        const int colg = n0 - 2048 + cl;
        const int hd = colg >> 6, d = colg & 63;
        const int row0 = m0 + wm * 64 + mi * 16 + (ln >> 4) * 4;
        const int bI = row0 >> 11, s = row0 & 2047;
        const float bias = bb[nb + cl];
        f16x4 pv;
#pragma unroll
        for (int r = 0; r < 4; ++r) pv[r] = (f16)(acc[mi][nf][r] + bias);
        *(f16x4*)(&Vt[((size_t)(bI * 16 + hd) * 64 + d) * SEQ + s]) = pv;
      }
  } else {
    const float sc = (MODE == 0 && n0 < 1024) ? QSCALE : 1.0f;
#pragma unroll
    for (int mi = 0; mi < 4; ++mi)
#pragma unroll
      for (int nf = 0; nf < 2; ++nf)
#pragma unroll
        for (int r = 0; r < 4; ++r) {
          const int row = m0 + wm * 64 + mi * 16 + (ln >> 4) * 4 + r;
          const int cl = wn * 32 + nf * 16 + (ln & 15);
          const float val = (acc[mi][nf][r] + bb[nb + cl]) * sc;
          if (MODE == 1)
            ((float*)Cout)[(size_t)row * Nd + n0 + cl] = val;
          else
            ((f16*)Cout)[(size_t)row * Nd + n0 + cl] = (f16)val;
        }
  }
}

// ---- fused sigmoid attention: 32x32 MFMA, in-register P, kv-split 2 ----
__global__ __launch_bounds__(256, 2) void k_attn(const f16* __restrict__ QKV,
                                                 const f16* __restrict__ Vt,
                                                 f16* __restrict__ Opart) {
  __shared__ __align__(16) f16 Ks[2][4096];  // [kv 64][d 64] swizzled
  __shared__ __align__(16) f16 Vs[2][4096];  // [d 64][kv 64] swizzled
  int id = blockIdx.x;
  id = (id & 7) * 128 + (id >> 3);  // XCD swizzle (grid 1024)
  const int qt = id & 15, hd = (id >> 4) & 15, b = (id >> 8) & 1, half = id >> 9;
  const int tid = threadIdx.x, w = tid >> 6, ln = tid & 63;
  const int lh = ln >> 5, l31 = ln & 31;
  const int q0 = qt * 128 + w * 32;
  const int kvbase = half * (SEQ / 2);
  const f16* Qb = QKV + ((size_t)b * SEQ) * NQKV + hd * 64;
  const f16* Kb = QKV + ((size_t)b * SEQ) * NQKV + 1024 + hd * 64;
  const f16* Vtb = Vt + (size_t)(b * N_HEAD + hd) * 64 * SEQ;

  // Q B-fragments in registers: lane q-row = q0 + l31, d = kk*16 + lh*8 + j
  f16x8 aq[4];
#pragma unroll
  for (int kk = 0; kk < 4; ++kk)
    aq[kk] = *(const f16x8*)(Qb + (size_t)(q0 + l31) * NQKV + kk * 16 + lh * 8);

  f32x16 oacc0 = {}, oacc1 = {};

  auto stage = [&](int buf, int kt) {
    const int kv0 = kvbase + kt * 64;
#pragma unroll
    for (int i = 0; i < 2; ++i) {
      const int c = w * 2 + i;
      const int r = c * 8 + (ln >> 3);
      const int g = ln & 7;
      llds16(Kb + (size_t)(kv0 + r) * NQKV + ((g ^ (r & 7)) * 8), &Ks[buf][c * 512]);
      llds16(Vtb + (size_t)r * SEQ + kv0 + ((g ^ (r & 7)) * 8), &Vs[buf][c * 512]);
    }
  };
  stage(0, 0);
  __syncthreads();
  int cur = 0;
  for (int kt = 0; kt < SEQ / 128; ++kt) {
    if (kt < SEQ / 128 - 1) stage(cur ^ 1, kt + 1);
    // S^T = K @ Q^T : lane q = l31 fixed; kv = kvt*32 + (reg&3)+8*(reg>>2)+4*lh
    f32x16 sacc0 = {}, sacc1 = {};
#pragma unroll
    for (int kk = 0; kk < 4; ++kk) {
      {
        const int r = l31;
        const f16x8 ak = *(const f16x8*)(&Ks[cur][r * 64 + (((kk * 2 + lh) ^ (r & 7)) * 8)]);
        sacc0 = __builtin_amdgcn_mfma_f32_32x32x16_f16(ak, aq[kk], sacc0, 0, 0, 0);
      }
      {
        const int r = 32 + l31;
        const f16x8 ak = *(const f16x8*)(&Ks[cur][r * 64 + (((kk * 2 + lh) ^ (r & 7)) * 8)]);
        sacc1 = __builtin_amdgcn_mfma_f32_32x32x16_f16(ak, aq[kk], sacc1, 0, 0, 0);
      }
    }
    // P = sigmoid: exp2 with folded scale; pack + permlane32_swap -> PV A-frags
    f16x8 pa[4];
#pragma unroll
    for (int kvt = 0; kvt < 2; ++kvt) {
      const f32x16 sc = kvt ? sacc1 : sacc0;
#pragma unroll
      for (int hf = 0; hf < 2; ++hf) {
        const int b8 = hf * 8;
        u32 X = pk2(SIG(sc[b8 + 0]), SIG(sc[b8 + 1]));
        u32 Y = pk2(SIG(sc[b8 + 2]), SIG(sc[b8 + 3]));
        u32 Z = pk2(SIG(sc[b8 + 4]), SIG(sc[b8 + 5]));
        u32 W = pk2(SIG(sc[b8 + 6]), SIG(sc[b8 + 7]));
        asm volatile("v_permlane32_swap_b32 %0, %1" : "+v"(X), "+v"(Z));
        asm volatile("v_permlane32_swap_b32 %0, %1" : "+v"(Y), "+v"(W));
        union { u32 uw[4]; f16x8 v; } u;
        u.uw[0] = X; u.uw[1] = Y; u.uw[2] = Z; u.uw[3] = W;
        pa[kvt * 2 + hf] = u.v;
      }
    }
    // O += P @ V : B-frag from Vs rows d, k-rows kv = c*16 + lh*8 + j
#pragma unroll
    for (int c = 0; c < 4; ++c) {
      {
        const int d = l31;
        const f16x8 bv = *(const f16x8*)(&Vs[cur][d * 64 + (((c * 2 + lh) ^ (d & 7)) * 8)]);
        oacc0 = __builtin_amdgcn_mfma_f32_32x32x16_f16(pa[c], bv, oacc0, 0, 0, 0);
      }
      {
        const int d = 32 + l31;
        const f16x8 bv = *(const f16x8*)(&Vs[cur][d * 64 + (((c * 2 + lh) ^ (d & 7)) * 8)]);
        oacc1 = __builtin_amdgcn_mfma_f32_32x32x16_f16(pa[c], bv, oacc1, 0, 0, 0);
      }
    }
    __syncthreads();
    cur ^= 1;
  }
  // write partial O: col = hd*64 + dt*32 + l31, row q = q0 + (r&3)+8*(r>>2)+4*lh
  f16* ob = Opart + (size_t)half * MTOT * D_MODEL;
#pragma unroll
  for (int dt = 0; dt < 2; ++dt) {
    const int dcol = hd * 64 + dt * 32 + l31;
#pragma unroll
    for (int r = 0; r < 16; ++r) {
      const int ql = (r & 3) + 8 * (r >> 2) + 4 * lh;
      const float v = dt ? oacc1[r] : oacc0[r];
      ob[((size_t)b * SEQ + q0 + ql) * D_MODEL + dcol] = (f16)v;
    }
  }
}

// ---- sum the two kv-half partials into ctx ----
__global__ void k_add(const f16* __restrict__ a, const f16* __restrict__ b,
                      f16* __restrict__ o) {
  const int i = (blockIdx.x * 256 + threadIdx.x) * 8;
  const f16x8 x = *(const f16x8*)(a + i);
  const f16x8 y = *(const f16x8*)(b + i);
  f16x8 r;
#pragma unroll
  for (int j = 0; j < 8; ++j) r[j] = (f16)((float)x[j] + (float)y[j]);
  *(f16x8*)(o + i) = r;
}

extern "C" void kernel_launch(void* const* d_in, const int* in_sizes, int n_in,
                              void* d_out, int out_size, void* d_ws, size_t ws_size,
                              hipStream_t stream) {
  (void)in_sizes; (void)n_in; (void)out_size; (void)ws_size;
  const float* q  = (const float*)d_in[0];
  const float* k  = (const float*)d_in[1];
  const float* v  = (const float*)d_in[2];
  const float* Wq = (const float*)d_in[3];
  const float* bq = (const float*)d_in[4];
  const float* Wk = (const float*)d_in[5];
  const float* bk = (const float*)d_in[6];
  const float* Wv = (const float*)d_in[7];
  const float* bv = (const float*)d_in[8];
  const float* Wo = (const float*)d_in[9];
  const float* bo = (const float*)d_in[10];
  float* out = (float*)d_out;

  char* p = (char*)d_ws;
  const size_t SZ_X = (size_t)MTOT * D_MODEL * sizeof(f16);  // 8 MB
  f16* qb    = (f16*)p; p += 3 * SZ_X;                       // q,k,v contiguous
  f16* WqkvT = (f16*)p; p += 3 * (size_t)1024 * 1024 * sizeof(f16);
  f16* WoT   = (f16*)p; p += (size_t)1024 * 1024 * sizeof(f16);
  f16* QKVb  = (f16*)p; p += (size_t)MTOT * NQKV * sizeof(f16);  // 24 MB
  f16* Vtb   = (f16*)p; p += SZ_X;
  f16* Opart = (f16*)p; p += 2 * SZ_X;
  f16* ctx   = (f16*)p; p += SZ_X;
  f16* kb = qb + (size_t)MTOT * D_MODEL;
  f16* vb = kb + (size_t)MTOT * D_MODEL;

  k_cvt3<<<3 * MTOT * D_MODEL / 2048, 256, 0, stream>>>(q, k, v, qb);
  k_tw<<<dim3(32, 32, 4), dim3(32, 8), 0, stream>>>(Wq, Wk, Wv, Wo, WqkvT, WoT);
  k_gemm<NQKV, 0><<<(MTOT / 128) * (NQKV / 128), 512, 0, stream>>>(
      qb, kb, vb, WqkvT, bq, bk, bv, QKVb, Vtb);
  k_attn<<<(SEQ / 128) * N_HEAD * BATCH * 2, 256, 0, stream>>>(QKVb, Vtb, Opart);
  k_add<<<MTOT * D_MODEL / 2048, 256, 0, stream>>>(
      Opart, Opart + (size_t)MTOT * D_MODEL, ctx);
  k_gemm<1024, 1><<<(MTOT / 128) * (1024 / 128), 512, 0, stream>>>(
      ctx, ctx, ctx, WoT, bo, bo, bo, out, nullptr);
}

// Round 8
// 233.354 us; speedup vs baseline: 1.0043x; 1.0043x over previous
//
#include <hip/hip_runtime.h>
#include <stdint.h>
#include <math.h>

typedef _Float16 f16;
typedef _Float16 f16x4 __attribute__((ext_vector_type(4)));
typedef _Float16 f16x8 __attribute__((ext_vector_type(8)));
typedef float f32x4 __attribute__((ext_vector_type(4)));
typedef float f32x16 __attribute__((ext_vector_type(16)));
typedef unsigned int u32;

#define D_MODEL 1024
#define N_HEAD 16
#define BATCH 2
#define SEQ 2048
#define MTOT 4096
#define NQKV 3072
#define KVSPLIT 4
// 0.125 * log2(e): folded into Q so sigmoid(x/8) = 1/(1+exp2(-Qs.K))
#define QSCALE 0.18033688011112042f

__device__ __forceinline__ void llds16(const void* g, void* l) {
  __builtin_amdgcn_global_load_lds(
      (const __attribute__((address_space(1))) unsigned int*)g,
      (__attribute__((address_space(3))) unsigned int*)l, 16, 0, 0);
}

__device__ __forceinline__ float fast_rcp(float x) {
#if __has_builtin(__builtin_amdgcn_rcpf)
  return __builtin_amdgcn_rcpf(x);
#else
  return 1.0f / x;
#endif
}

__device__ __forceinline__ float fast_exp2(float x) {
#if __has_builtin(__builtin_amdgcn_exp2f)
  return __builtin_amdgcn_exp2f(x);
#else
  return exp2f(x);
#endif
}

// sigmoid with pre-scaled scores: s already = (Q.K/8)*log2e
#define SIG(s) fast_rcp(1.0f + fast_exp2(-(s)))

__device__ __forceinline__ u32 pk2(float a, float b) {
  auto h = __builtin_amdgcn_cvt_pkrtz(a, b);  // __fp16 ext_vector(2)
  return __builtin_bit_cast(u32, h);
}

// ---- fused fp32->fp16 convert of q,k,v (contiguous 12M-elem dest) ----
__global__ void k_cvt3(const float* __restrict__ q, const float* __restrict__ k,
                       const float* __restrict__ v, f16* __restrict__ dst) {
  const int idx = (blockIdx.x * 256 + threadIdx.x) * 8;
  const int seg = idx >> 22;
  const int off = idx & ((1 << 22) - 1);
  const float* s = (seg == 0) ? q : (seg == 1) ? k : v;
  const float4 a = *(const float4*)(s + off);
  const float4 b = *(const float4*)(s + off + 4);
  f16x8 o;
  o[0] = (f16)a.x; o[1] = (f16)a.y; o[2] = (f16)a.z; o[3] = (f16)a.w;
  o[4] = (f16)b.x; o[5] = (f16)b.y; o[6] = (f16)b.z; o[7] = (f16)b.w;
  *(f16x8*)(dst + idx) = o;
}

// ---- all 4 weights [K][N] fp32 -> [N][K] fp16 in one launch ----
__global__ void k_tw(const float* __restrict__ Wq, const float* __restrict__ Wk,
                     const float* __restrict__ Wv, const float* __restrict__ Wo,
                     f16* __restrict__ WqkvT, f16* __restrict__ WoT) {
  __shared__ float t[32][33];
  const int z = blockIdx.z;
  const float* W = (z == 0) ? Wq : (z == 1) ? Wk : (z == 2) ? Wv : Wo;
  f16* dst = (z < 3) ? (WqkvT + (size_t)z * 1024 * 1024) : WoT;
  const int bx = blockIdx.x * 32, by = blockIdx.y * 32;
  const int tx = threadIdx.x, ty = threadIdx.y;
#pragma unroll
  for (int i = 0; i < 32; i += 8)
    t[ty + i][tx] = W[(size_t)(by + ty + i) * 1024 + bx + tx];
  __syncthreads();
#pragma unroll
  for (int i = 0; i < 32; i += 8)
    dst[(size_t)(bx + ty + i) * 1024 + by + tx] = (f16)t[tx][ty + i];
}

// ---- GEMM: C[4096, Nd]. MODE 0: fused QKV, f16 out; Q-third scaled by QSCALE;
//      V-third written transposed to Vt[(b,h),d,s]. MODE 1: fp32 out. ----
template <int Nd, int MODE>
__global__ __launch_bounds__(512, 4) void k_gemm(const f16* __restrict__ A0,
                                                 const f16* __restrict__ A1,
                                                 const f16* __restrict__ A2,
                                                 const f16* __restrict__ BT,
                                                 const float* __restrict__ b0,
                                                 const float* __restrict__ b1,
                                                 const float* __restrict__ b2,
                                                 void* __restrict__ Cout,
                                                 f16* __restrict__ Vt) {
  constexpr int Kd = 1024;
  constexpr int NBX = Nd / 128;
  constexpr int NWG = (MTOT / 128) * NBX;
  __shared__ __align__(16) f16 As[2][8192];
  __shared__ __align__(16) f16 Bs[2][8192];
  int id = blockIdx.x;
  id = (id & 7) * (NWG / 8) + (id >> 3);
  const int n0 = (id % NBX) * 128, m0 = (id / NBX) * 128;
  const f16* A = (Nd == 1024) ? A0 : (n0 < 1024 ? A0 : n0 < 2048 ? A1 : A2);
  const int tid = threadIdx.x, w = tid >> 6, ln = tid & 63;
  const int wm = w >> 2, wn = w & 3;
  f32x4 acc[4][2] = {};

  auto stage = [&](int buf, int kt) {
    const int k0 = kt * 64;
#pragma unroll
    for (int i = 0; i < 2; ++i) {
      const int c = w * 2 + i;
      const int r = c * 8 + (ln >> 3);
      const int g = ln & 7;
      const int ko = k0 + ((g ^ (r & 7)) * 8);
      llds16(A + (size_t)(m0 + r) * Kd + ko, &As[buf][c * 512]);
      llds16(BT + (size_t)(n0 + r) * Kd + ko, &Bs[buf][c * 512]);
    }
  };
  stage(0, 0);
  __syncthreads();
  int cur = 0;
  for (int kt = 0; kt < Kd / 64; ++kt) {
    if (kt < Kd / 64 - 1) stage(cur ^ 1, kt + 1);
#pragma unroll
    for (int kk = 0; kk < 2; ++kk) {
      f16x8 af[4], bf[2];
#pragma unroll
      for (int mi = 0; mi < 4; ++mi) {
        const int r = wm * 64 + mi * 16 + (ln & 15);
        const int g = kk * 4 + (ln >> 4);
        af[mi] = *(const f16x8*)(&As[cur][r * 64 + ((g ^ (r & 7)) * 8)]);
      }
#pragma unroll
      for (int nf = 0; nf < 2; ++nf) {
        const int r = wn * 32 + nf * 16 + (ln & 15);
        const int g = kk * 4 + (ln >> 4);
        bf[nf] = *(const f16x8*)(&Bs[cur][r * 64 + ((g ^ (r & 7)) * 8)]);
      }
      __builtin_amdgcn_s_setprio(1);
#pragma unroll
      for (int mi = 0; mi < 4; ++mi)
#pragma unroll
        for (int nf = 0; nf < 2; ++nf)
          acc[mi][nf] = __builtin_amdgcn_mfma_f32_16x16x32_f16(af[mi], bf[nf], acc[mi][nf], 0, 0, 0);
      __builtin_amdgcn_s_setprio(0);
    }
    __syncthreads();
    cur ^= 1;
  }
  const float* bb = (Nd == 1024) ? b0 : (n0 < 1024 ? b0 : n0 < 2048 ? b1 : b2);
  const int nb = n0 & 1023;
  if (MODE == 0 && n0 >= 2048) {
    // V third: write transposed into Vt[(b,h), d, s], 8B packed along s
#pragma unroll
    for (int mi = 0; mi < 4; ++mi)
#pragma unroll
      for (int nf = 0; nf < 2; ++nf) {
        const int cl = wn * 32 + nf * 16 + (ln & 15);
        const int colg = n0 - 2048 + cl;
        const int hd = colg >> 6, d = colg & 63;
        const int row0 = m0 + wm * 64 + mi * 16 + (ln >> 4) * 4;
        const int bI = row0 >> 11, s = row0 & 2047;
        const float bias = bb[nb + cl];
        f16x4 pv;
#pragma unroll
        for (int r = 0; r < 4; ++r) pv[r] = (f16)(acc[mi][nf][r] + bias);
        *(f16x4*)(&Vt[((size_t)(bI * 16 + hd) * 64 + d) * SEQ + s]) = pv;
      }
  } else {
    const float sc = (MODE == 0 && n0 < 1024) ? QSCALE : 1.0f;
#pragma unroll
    for (int mi = 0; mi < 4; ++mi)
#pragma unroll
      for (int nf = 0; nf < 2; ++nf)
#pragma unroll
        for (int r = 0; r < 4; ++r) {
          const int row = m0 + wm * 64 + mi * 16 + (ln >> 4) * 4 + r;
          const int cl = wn * 32 + nf * 16 + (ln & 15);
          const float val = (acc[mi][nf][r] + bb[nb + cl]) * sc;
          if (MODE == 1)
            ((float*)Cout)[(size_t)row * Nd + n0 + cl] = val;
          else
            ((f16*)Cout)[(size_t)row * Nd + n0 + cl] = (f16)val;
        }
  }
}

// ---- fused sigmoid attention: 32x32 MFMA, in-register P, kv-split 4 ----
__global__ __launch_bounds__(256, 2) void k_attn(const f16* __restrict__ QKV,
                                                 const f16* __restrict__ Vt,
                                                 f16* __restrict__ Opart) {
  __shared__ __align__(16) f16 Ks[2][4096];  // [kv 64][d 64] swizzled
  __shared__ __align__(16) f16 Vs[2][4096];  // [d 64][kv 64] swizzled
  int id = blockIdx.x;
  id = (id & 7) * 256 + (id >> 3);  // XCD swizzle (grid 2048)
  const int qt = id & 15, hd = (id >> 4) & 15, b = (id >> 8) & 1, qr = id >> 9;
  const int tid = threadIdx.x, w = tid >> 6, ln = tid & 63;
  const int lh = ln >> 5, l31 = ln & 31;
  const int q0 = qt * 128 + w * 32;
  const int kvbase = qr * (SEQ / KVSPLIT);
  const f16* Qb = QKV + ((size_t)b * SEQ) * NQKV + hd * 64;
  const f16* Kb = QKV + ((size_t)b * SEQ) * NQKV + 1024 + hd * 64;
  const f16* Vtb = Vt + (size_t)(b * N_HEAD + hd) * 64 * SEQ;

  // Q B-fragments in registers: lane q-row = q0 + l31, d = kk*16 + lh*8 + j
  f16x8 aq[4];
#pragma unroll
  for (int kk = 0; kk < 4; ++kk)
    aq[kk] = *(const f16x8*)(Qb + (size_t)(q0 + l31) * NQKV + kk * 16 + lh * 8);

  f32x16 oacc0 = {}, oacc1 = {};

  auto stage = [&](int buf, int kt) {
    const int kv0 = kvbase + kt * 64;
#pragma unroll
    for (int i = 0; i < 2; ++i) {
      const int c = w * 2 + i;
      const int r = c * 8 + (ln >> 3);
      const int g = ln & 7;
      llds16(Kb + (size_t)(kv0 + r) * NQKV + ((g ^ (r & 7)) * 8), &Ks[buf][c * 512]);
      llds16(Vtb + (size_t)r * SEQ + kv0 + ((g ^ (r & 7)) * 8), &Vs[buf][c * 512]);
    }
  };
  stage(0, 0);
  __syncthreads();
  int cur = 0;
  for (int kt = 0; kt < SEQ / KVSPLIT / 64; ++kt) {
    if (kt < SEQ / KVSPLIT / 64 - 1) stage(cur ^ 1, kt + 1);
    // S^T = K @ Q^T : lane q = l31 fixed; kv = kvt*32 + (reg&3)+8*(reg>>2)+4*lh
    f32x16 sacc0 = {}, sacc1 = {};
    __builtin_amdgcn_s_setprio(1);
#pragma unroll
    for (int kk = 0; kk < 4; ++kk) {
      {
        const int r = l31;
        const f16x8 ak = *(const f16x8*)(&Ks[cur][r * 64 + (((kk * 2 + lh) ^ (r & 7)) * 8)]);
        sacc0 = __builtin_amdgcn_mfma_f32_32x32x16_f16(ak, aq[kk], sacc0, 0, 0, 0);
      }
      {
        const int r = 32 + l31;
        const f16x8 ak = *(const f16x8*)(&Ks[cur][r * 64 + (((kk * 2 + lh) ^ (r & 7)) * 8)]);
        sacc1 = __builtin_amdgcn_mfma_f32_32x32x16_f16(ak, aq[kk], sacc1, 0, 0, 0);
      }
    }
    __builtin_amdgcn_s_setprio(0);
    // P = sigmoid: exp2 with folded scale; pack + permlane32_swap -> PV A-frags
    f16x8 pa[4];
#pragma unroll
    for (int kvt = 0; kvt < 2; ++kvt) {
      const f32x16 sc = kvt ? sacc1 : sacc0;
#pragma unroll
      for (int hf = 0; hf < 2; ++hf) {
        const int b8 = hf * 8;
        u32 X = pk2(SIG(sc[b8 + 0]), SIG(sc[b8 + 1]));
        u32 Y = pk2(SIG(sc[b8 + 2]), SIG(sc[b8 + 3]));
        u32 Z = pk2(SIG(sc[b8 + 4]), SIG(sc[b8 + 5]));
        u32 W = pk2(SIG(sc[b8 + 6]), SIG(sc[b8 + 7]));
        asm volatile("v_permlane32_swap_b32 %0, %1" : "+v"(X), "+v"(Z));
        asm volatile("v_permlane32_swap_b32 %0, %1" : "+v"(Y), "+v"(W));
        union { u32 uw[4]; f16x8 v; } u;
        u.uw[0] = X; u.uw[1] = Y; u.uw[2] = Z; u.uw[3] = W;
        pa[kvt * 2 + hf] = u.v;
      }
    }
    // O += P @ V : B-frag from Vs rows d, k-rows kv = c*16 + lh*8 + j
    __builtin_amdgcn_s_setprio(1);
#pragma unroll
    for (int c = 0; c < 4; ++c) {
      {
        const int d = l31;
        const f16x8 bv = *(const f16x8*)(&Vs[cur][d * 64 + (((c * 2 + lh) ^ (d & 7)) * 8)]);
        oacc0 = __builtin_amdgcn_mfma_f32_32x32x16_f16(pa[c], bv, oacc0, 0, 0, 0);
      }
      {
        const int d = 32 + l31;
        const f16x8 bv = *(const f16x8*)(&Vs[cur][d * 64 + (((c * 2 + lh) ^ (d & 7)) * 8)]);
        oacc1 = __builtin_amdgcn_mfma_f32_32x32x16_f16(pa[c], bv, oacc1, 0, 0, 0);
      }
    }
    __builtin_amdgcn_s_setprio(0);
    __syncthreads();
    cur ^= 1;
  }
  // write partial O: col = hd*64 + dt*32 + l31, row q = q0 + (r&3)+8*(r>>2)+4*lh
  f16* ob = Opart + (size_t)qr * MTOT * D_MODEL;
#pragma unroll
  for (int dt = 0; dt < 2; ++dt) {
    const int dcol = hd * 64 + dt * 32 + l31;
#pragma unroll
    for (int r = 0; r < 16; ++r) {
      const int ql = (r & 3) + 8 * (r >> 2) + 4 * lh;
      const float v = dt ? oacc1[r] : oacc0[r];
      ob[((size_t)b * SEQ + q0 + ql) * D_MODEL + dcol] = (f16)v;
    }
  }
}

// ---- sum the four kv-quarter partials into ctx ----
__global__ void k_add4(const f16* __restrict__ a, f16* __restrict__ o) {
  const size_t plane = (size_t)MTOT * D_MODEL;
  const int i = (blockIdx.x * 256 + threadIdx.x) * 8;
  const f16x8 x0 = *(const f16x8*)(a + i);
  const f16x8 x1 = *(const f16x8*)(a + plane + i);
  const f16x8 x2 = *(const f16x8*)(a + 2 * plane + i);
  const f16x8 x3 = *(const f16x8*)(a + 3 * plane + i);
  f16x8 r;
#pragma unroll
  for (int j = 0; j < 8; ++j)
    r[j] = (f16)(((float)x0[j] + (float)x1[j]) + ((float)x2[j] + (float)x3[j]));
  *(f16x8*)(o + i) = r;
}

extern "C" void kernel_launch(void* const* d_in, const int* in_sizes, int n_in,
                              void* d_out, int out_size, void* d_ws, size_t ws_size,
                              hipStream_t stream) {
  (void)in_sizes; (void)n_in; (void)out_size; (void)ws_size;
  const float* q  = (const float*)d_in[0];
  const float* k  = (const float*)d_in[1];
  const float* v  = (const float*)d_in[2];
  const float* Wq = (const float*)d_in[3];
  const float* bq = (const float*)d_in[4];
  const float* Wk = (const float*)d_in[5];
  const float* bk = (const float*)d_in[6];
  const float* Wv = (const float*)d_in[7];
  const float* bv = (const float*)d_in[8];
  const float* Wo = (const float*)d_in[9];
  const float* bo = (const float*)d_in[10];
  float* out = (float*)d_out;

  char* p = (char*)d_ws;
  const size_t SZ_X = (size_t)MTOT * D_MODEL * sizeof(f16);  // 8 MB
  f16* qb    = (f16*)p; p += 3 * SZ_X;                       // q,k,v contiguous
  f16* WqkvT = (f16*)p; p += 3 * (size_t)1024 * 1024 * sizeof(f16);
  f16* WoT   = (f16*)p; p += (size_t)1024 * 1024 * sizeof(f16);
  f16* QKVb  = (f16*)p; p += (size_t)MTOT * NQKV * sizeof(f16);  // 24 MB
  f16* Vtb   = (f16*)p; p += SZ_X;
  f16* Opart = (f16*)p; p += KVSPLIT * SZ_X;
  f16* kb = qb + (size_t)MTOT * D_MODEL;
  f16* vb = kb + (size_t)MTOT * D_MODEL;
  f16* ctx = qb;  // reuse: qb dead after QKV GEMM

  k_cvt3<<<3 * MTOT * D_MODEL / 2048, 256, 0, stream>>>(q, k, v, qb);
  k_tw<<<dim3(32, 32, 4), dim3(32, 8), 0, stream>>>(Wq, Wk, Wv, Wo, WqkvT, WoT);
  k_gemm<NQKV, 0><<<(MTOT / 128) * (NQKV / 128), 512, 0, stream>>>(
      qb, kb, vb, WqkvT, bq, bk, bv, QKVb, Vtb);
  k_attn<<<(SEQ / 128) * N_HEAD * BATCH * KVSPLIT, 256, 0, stream>>>(QKVb, Vtb, Opart);
  k_add4<<<MTOT * D_MODEL / 2048, 256, 0, stream>>>(Opart, ctx);
  k_gemm<1024, 1><<<(MTOT / 128) * (1024 / 128), 512, 0, stream>>>(
      ctx, ctx, ctx, WoT, bo, bo, bo, out, nullptr);
}

// Round 10
// 228.409 us; speedup vs baseline: 1.0260x; 1.0217x over previous
//
#include <hip/hip_runtime.h>
#include <stdint.h>
#include <math.h>

typedef _Float16 f16;
typedef _Float16 f16x4 __attribute__((ext_vector_type(4)));
typedef _Float16 f16x8 __attribute__((ext_vector_type(8)));
typedef float f32x4 __attribute__((ext_vector_type(4)));
typedef float f32x16 __attribute__((ext_vector_type(16)));
typedef unsigned int u32;

#define D_MODEL 1024
#define N_HEAD 16
#define BATCH 2
#define SEQ 2048
#define MTOT 4096
#define NQKV 3072
// 0.125 * log2(e): folded into Q so sigmoid(x/8) = 1/(1+exp2(-Qs.K))
#define QSCALE 0.18033688011112042f

__device__ __forceinline__ void llds16(const void* g, void* l) {
  __builtin_amdgcn_global_load_lds(
      (const __attribute__((address_space(1))) unsigned int*)g,
      (__attribute__((address_space(3))) unsigned int*)l, 16, 0, 0);
}

__device__ __forceinline__ float fast_rcp(float x) {
#if __has_builtin(__builtin_amdgcn_rcpf)
  return __builtin_amdgcn_rcpf(x);
#else
  return 1.0f / x;
#endif
}

__device__ __forceinline__ float fast_exp2(float x) {
#if __has_builtin(__builtin_amdgcn_exp2f)
  return __builtin_amdgcn_exp2f(x);
#else
  return exp2f(x);
#endif
}

#define SIG(s) fast_rcp(1.0f + fast_exp2(-(s)))

__device__ __forceinline__ u32 pk2(float a, float b) {
  auto h = __builtin_amdgcn_cvt_pkrtz(a, b);
  return __builtin_bit_cast(u32, h);
}

// ---- fused fp32->fp16 convert of q,k,v ----
__global__ void k_cvt3(const float* __restrict__ q, const float* __restrict__ k,
                       const float* __restrict__ v, f16* __restrict__ dst) {
  const int idx = (blockIdx.x * 256 + threadIdx.x) * 8;
  const int seg = idx >> 22;
  const int off = idx & ((1 << 22) - 1);
  const float* s = (seg == 0) ? q : (seg == 1) ? k : v;
  const float4 a = *(const float4*)(s + off);
  const float4 b = *(const float4*)(s + off + 4);
  f16x8 o;
  o[0] = (f16)a.x; o[1] = (f16)a.y; o[2] = (f16)a.z; o[3] = (f16)a.w;
  o[4] = (f16)b.x; o[5] = (f16)b.y; o[6] = (f16)b.z; o[7] = (f16)b.w;
  *(f16x8*)(dst + idx) = o;
}

// ---- all 4 weights [K][N] fp32 -> [N][K] fp16 ----
__global__ void k_tw(const float* __restrict__ Wq, const float* __restrict__ Wk,
                     const float* __restrict__ Wv, const float* __restrict__ Wo,
                     f16* __restrict__ WqkvT, f16* __restrict__ WoT) {
  __shared__ float t[32][33];
  const int z = blockIdx.z;
  const float* W = (z == 0) ? Wq : (z == 1) ? Wk : (z == 2) ? Wv : Wo;
  f16* dst = (z < 3) ? (WqkvT + (size_t)z * 1024 * 1024) : WoT;
  const int bx = blockIdx.x * 32, by = blockIdx.y * 32;
  const int tx = threadIdx.x, ty = threadIdx.y;
#pragma unroll
  for (int i = 0; i < 32; i += 8)
    t[ty + i][tx] = W[(size_t)(by + ty + i) * 1024 + bx + tx];
  __syncthreads();
#pragma unroll
  for (int i = 0; i < 32; i += 8)
    dst[(size_t)(bx + ty + i) * 1024 + by + tx] = (f16)t[tx][ty + i];
}

// ---- QKV GEMM: 256x256 tile, BK=64, 8 waves (2Mx4N), counted-vmcnt 2-deep
//      prefetch, 4 quadrant phases per K-tile, setprio around MFMA. ----
__global__ __launch_bounds__(512, 2) void k_gemm256(const f16* __restrict__ A0,
                                                    const f16* __restrict__ A1,
                                                    const f16* __restrict__ A2,
                                                    const f16* __restrict__ BT,
                                                    const float* __restrict__ b0,
                                                    const float* __restrict__ b1,
                                                    const float* __restrict__ b2,
                                                    f16* __restrict__ Cout,
                                                    f16* __restrict__ Vt) {
  constexpr int Kd = 1024, NT = Kd / 64;
  constexpr int NBX = NQKV / 256;  // 12
  constexpr int NWG = (MTOT / 256) * NBX;  // 192 (not %8: use bijective swz)
  __shared__ __align__(16) f16 As[2][256 * 64];
  __shared__ __align__(16) f16 Bs[2][256 * 64];
  // bijective XCD swizzle for NWG=192 (q=24, r=0)
  int id = blockIdx.x;
  id = (id & 7) * (NWG / 8) + (id >> 3);
  const int n0 = (id % NBX) * 256, m0 = (id / NBX) * 256;
  const f16* A = (n0 < 1024) ? A0 : (n0 < 2048 ? A1 : A2);
  const int tid = threadIdx.x, w = tid >> 6, ln = tid & 63;
  const int wm = w >> 2, wn = w & 3;

  f32x4 acc[8][4] = {};

  // stage K-tile kt into buffer d: per lane 4 A-loads + 4 B-loads.
  auto stage = [&](int d, int kt) {
    const int k0 = kt * 64;
    const int rsub = w * 8 + (ln >> 3);          // 0..63 within each 64-row group
    const int gsw = ((ln & 7) ^ (ln >> 3)) * 8;  // pre-swizzled source granule
#pragma unroll
    for (int i = 0; i < 4; ++i) {
      const int r = i * 64 + rsub;
      llds16(A + (size_t)(m0 + r) * Kd + k0 + gsw, &As[d][(i * 64 + w * 8) * 64]);
    }
#pragma unroll
    for (int i = 0; i < 4; ++i) {
      const int r = i * 64 + rsub;
      llds16(BT + (size_t)(n0 + r) * Kd + k0 + gsw, &Bs[d][(i * 64 + w * 8) * 64]);
    }
  };

  stage(0, 0);
  stage(1, 1);
  for (int t = 0; t < NT; ++t) {
    const int d = t & 1;
    // wait this tile's 8 loads (next tile's 8 may stay in flight); never drain
    if (t + 1 < NT) {
      asm volatile("s_waitcnt vmcnt(8)" ::: "memory");
    } else {
      asm volatile("s_waitcnt vmcnt(0)" ::: "memory");
    }
    __builtin_amdgcn_sched_barrier(0);
    __builtin_amdgcn_s_barrier();
    __builtin_amdgcn_sched_barrier(0);
#pragma unroll
    for (int q = 0; q < 4; ++q) {
      const int mb = (q & 1) * 4, nb = (q >> 1) * 2;
      f16x8 af[4][2], bf[2][2];
#pragma unroll
      for (int kk = 0; kk < 2; ++kk) {
        const int g = kk * 4 + (ln >> 4);
#pragma unroll
        for (int mi = 0; mi < 4; ++mi) {
          const int r = wm * 128 + (mb + mi) * 16 + (ln & 15);
          af[mi][kk] = *(const f16x8*)(&As[d][r * 64 + ((g ^ (r & 7)) * 8)]);
        }
#pragma unroll
        for (int nf = 0; nf < 2; ++nf) {
          const int r = wn * 64 + (nb + nf) * 16 + (ln & 15);
          bf[nf][kk] = *(const f16x8*)(&Bs[d][r * 64 + ((g ^ (r & 7)) * 8)]);
        }
      }
      __builtin_amdgcn_s_setprio(1);
#pragma unroll
      for (int kk = 0; kk < 2; ++kk)
#pragma unroll
        for (int mi = 0; mi < 4; ++mi)
#pragma unroll
          for (int nf = 0; nf < 2; ++nf)
            acc[mb + mi][nb + nf] = __builtin_amdgcn_mfma_f32_16x16x32_f16(
                af[mi][kk], bf[nf][kk], acc[mb + mi][nb + nf], 0, 0, 0);
      __builtin_amdgcn_s_setprio(0);
    }
    __builtin_amdgcn_sched_barrier(0);
    __builtin_amdgcn_s_barrier();  // all waves done reading buf d
    __builtin_amdgcn_sched_barrier(0);
    if (t + 2 < NT) stage(d, t + 2);
  }

  const float* bb = (n0 < 1024) ? b0 : (n0 < 2048 ? b1 : b2);
  const int nb0 = n0 & 1023;
  if (n0 >= 2048) {
    // V third: write transposed into Vt[(b,h), d, s]
#pragma unroll
    for (int mi = 0; mi < 8; ++mi)
#pragma unroll
      for (int nf = 0; nf < 4; ++nf) {
        const int cl = wn * 64 + nf * 16 + (ln & 15);
        const int colg = n0 - 2048 + cl;
        const int hd = colg >> 6, dd = colg & 63;
        const int row0 = m0 + wm * 128 + mi * 16 + (ln >> 4) * 4;
        const int bI = row0 >> 11, s = row0 & 2047;
        const float bias = bb[nb0 + cl];
        f16x4 pv;
#pragma unroll
        for (int r = 0; r < 4; ++r) pv[r] = (f16)(acc[mi][nf][r] + bias);
        *(f16x4*)(&Vt[((size_t)(bI * 16 + hd) * 64 + dd) * SEQ + s]) = pv;
      }
  } else {
    const float sc = (n0 < 1024) ? QSCALE : 1.0f;
#pragma unroll
    for (int mi = 0; mi < 8; ++mi)
#pragma unroll
      for (int nf = 0; nf < 4; ++nf)
#pragma unroll
        for (int r = 0; r < 4; ++r) {
          const int row = m0 + wm * 128 + mi * 16 + (ln >> 4) * 4 + r;
          const int cl = wn * 64 + nf * 16 + (ln & 15);
          Cout[(size_t)row * NQKV + n0 + cl] =
              (f16)((acc[mi][nf][r] + bb[nb0 + cl]) * sc);
        }
  }
}

// ---- output projection: 128x128 tile, 2-phase (grid 256 = full chip) ----
__global__ __launch_bounds__(512, 4) void k_gemmO(const f16* __restrict__ A,
                                                  const f16* __restrict__ BT,
                                                  const float* __restrict__ bias,
                                                  float* __restrict__ Cout) {
  constexpr int Kd = 1024, Nd = 1024;
  constexpr int NBX = Nd / 128;
  constexpr int NWG = (MTOT / 128) * NBX;
  __shared__ __align__(16) f16 As[2][8192];
  __shared__ __align__(16) f16 Bs[2][8192];
  int id = blockIdx.x;
  id = (id & 7) * (NWG / 8) + (id >> 3);
  const int n0 = (id % NBX) * 128, m0 = (id / NBX) * 128;
  const int tid = threadIdx.x, w = tid >> 6, ln = tid & 63;
  const int wm = w >> 2, wn = w & 3;
  f32x4 acc[4][2] = {};

  auto stage = [&](int buf, int kt) {
    const int k0 = kt * 64;
#pragma unroll
    for (int i = 0; i < 2; ++i) {
      const int c = w * 2 + i;
      const int r = c * 8 + (ln >> 3);
      const int g = ln & 7;
      const int ko = k0 + ((g ^ (r & 7)) * 8);
      llds16(A + (size_t)(m0 + r) * Kd + ko, &As[buf][c * 512]);
      llds16(BT + (size_t)(n0 + r) * Kd + ko, &Bs[buf][c * 512]);
    }
  };
  stage(0, 0);
  __syncthreads();
  int cur = 0;
  for (int kt = 0; kt < Kd / 64; ++kt) {
    if (kt < Kd / 64 - 1) stage(cur ^ 1, kt + 1);
#pragma unroll
    for (int kk = 0; kk < 2; ++kk) {
      f16x8 af[4], bf[2];
#pragma unroll
      for (int mi = 0; mi < 4; ++mi) {
        const int r = wm * 64 + mi * 16 + (ln & 15);
        const int g = kk * 4 + (ln >> 4);
        af[mi] = *(const f16x8*)(&As[cur][r * 64 + ((g ^ (r & 7)) * 8)]);
      }
#pragma unroll
      for (int nf = 0; nf < 2; ++nf) {
        const int r = wn * 32 + nf * 16 + (ln & 15);
        const int g = kk * 4 + (ln >> 4);
        bf[nf] = *(const f16x8*)(&Bs[cur][r * 64 + ((g ^ (r & 7)) * 8)]);
      }
#pragma unroll
      for (int mi = 0; mi < 4; ++mi)
#pragma unroll
        for (int nf = 0; nf < 2; ++nf)
          acc[mi][nf] = __builtin_amdgcn_mfma_f32_16x16x32_f16(af[mi], bf[nf], acc[mi][nf], 0, 0, 0);
    }
    __syncthreads();
    cur ^= 1;
  }
#pragma unroll
  for (int mi = 0; mi < 4; ++mi)
#pragma unroll
    for (int nf = 0; nf < 2; ++nf)
#pragma unroll
      for (int r = 0; r < 4; ++r) {
        const int row = m0 + wm * 64 + mi * 16 + (ln >> 4) * 4 + r;
        const int cl = wn * 32 + nf * 16 + (ln & 15);
        Cout[(size_t)row * Nd + n0 + cl] = acc[mi][nf][r] + bias[n0 + cl];
      }
}

// ---- fused sigmoid attention: 32x32 MFMA, in-register P, kv-split 2 ----
__global__ __launch_bounds__(256, 2) void k_attn(const f16* __restrict__ QKV,
                                                 const f16* __restrict__ Vt,
                                                 f16* __restrict__ Opart) {
  __shared__ __align__(16) f16 Ks[2][4096];
  __shared__ __align__(16) f16 Vs[2][4096];
  int id = blockIdx.x;
  id = (id & 7) * 128 + (id >> 3);  // XCD swizzle (grid 1024)
  const int qt = id & 15, hd = (id >> 4) & 15, b = (id >> 8) & 1, half = id >> 9;
  const int tid = threadIdx.x, w = tid >> 6, ln = tid & 63;
  const int lh = ln >> 5, l31 = ln & 31;
  const int q0 = qt * 128 + w * 32;
  const int kvbase = half * (SEQ / 2);
  const f16* Qb = QKV + ((size_t)b * SEQ) * NQKV + hd * 64;
  const f16* Kb = QKV + ((size_t)b * SEQ) * NQKV + 1024 + hd * 64;
  const f16* Vtb = Vt + (size_t)(b * N_HEAD + hd) * 64 * SEQ;

  f16x8 aq[4];
#pragma unroll
  for (int kk = 0; kk < 4; ++kk)
    aq[kk] = *(const f16x8*)(Qb + (size_t)(q0 + l31) * NQKV + kk * 16 + lh * 8);

  f32x16 oacc0 = {}, oacc1 = {};

  auto stage = [&](int buf, int kt) {
    const int kv0 = kvbase + kt * 64;
#pragma unroll
    for (int i = 0; i < 2; ++i) {
      const int c = w * 2 + i;
      const int r = c * 8 + (ln >> 3);
      const int g = ln & 7;
      llds16(Kb + (size_t)(kv0 + r) * NQKV + ((g ^ (r & 7)) * 8), &Ks[buf][c * 512]);
      llds16(Vtb + (size_t)r * SEQ + kv0 + ((g ^ (r & 7)) * 8), &Vs[buf][c * 512]);
    }
  };
  stage(0, 0);
  __syncthreads();
  int cur = 0;
  for (int kt = 0; kt < SEQ / 128; ++kt) {
    if (kt < SEQ / 128 - 1) stage(cur ^ 1, kt + 1);
    f32x16 sacc0 = {}, sacc1 = {};
#pragma unroll
    for (int kk = 0; kk < 4; ++kk) {
      {
        const int r = l31;
        const f16x8 ak = *(const f16x8*)(&Ks[cur][r * 64 + (((kk * 2 + lh) ^ (r & 7)) * 8)]);
        sacc0 = __builtin_amdgcn_mfma_f32_32x32x16_f16(ak, aq[kk], sacc0, 0, 0, 0);
      }
      {
        const int r = 32 + l31;
        const f16x8 ak = *(const f16x8*)(&Ks[cur][r * 64 + (((kk * 2 + lh) ^ (r & 7)) * 8)]);
        sacc1 = __builtin_amdgcn_mfma_f32_32x32x16_f16(ak, aq[kk], sacc1, 0, 0, 0);
      }
    }
    f16x8 pa[4];
#pragma unroll
    for (int kvt = 0; kvt < 2; ++kvt) {
      const f32x16 sc = kvt ? sacc1 : sacc0;
#pragma unroll
      for (int hf = 0; hf < 2; ++hf) {
        const int b8 = hf * 8;
        u32 X = pk2(SIG(sc[b8 + 0]), SIG(sc[b8 + 1]));
        u32 Y = pk2(SIG(sc[b8 + 2]), SIG(sc[b8 + 3]));
        u32 Z = pk2(SIG(sc[b8 + 4]), SIG(sc[b8 + 5]));
        u32 W = pk2(SIG(sc[b8 + 6]), SIG(sc[b8 + 7]));
        asm volatile("v_permlane32_swap_b32 %0, %1" : "+v"(X), "+v"(Z));
        asm volatile("v_permlane32_swap_b32 %0, %1" : "+v"(Y), "+v"(W));
        union { u32 uw[4]; f16x8 v; } u;
        u.uw[0] = X; u.uw[1] = Y; u.uw[2] = Z; u.uw[3] = W;
        pa[kvt * 2 + hf] = u.v;
      }
    }
#pragma unroll
    for (int c = 0; c < 4; ++c) {
      {
        const int d = l31;
        const f16x8 bv = *(const f16x8*)(&Vs[cur][d * 64 + (((c * 2 + lh) ^ (d & 7)) * 8)]);
        oacc0 = __builtin_amdgcn_mfma_f32_32x32x16_f16(pa[c], bv, oacc0, 0, 0, 0);
      }
      {
        const int d = 32 + l31;
        const f16x8 bv = *(const f16x8*)(&Vs[cur][d * 64 + (((c * 2 + lh) ^ (d & 7)) * 8)]);
        oacc1 = __builtin_amdgcn_mfma_f32_32x32x16_f16(pa[c], bv, oacc1, 0, 0, 0);
      }
    }
    __syncthreads();
    cur ^= 1;
  }
  f16* ob = Opart + (size_t)half * MTOT * D_MODEL;
#pragma unroll
  for (int dt = 0; dt < 2; ++dt) {
    const int dcol = hd * 64 + dt * 32 + l31;
#pragma unroll
    for (int r = 0; r < 16; ++r) {
      const int ql = (r & 3) + 8 * (r >> 2) + 4 * lh;
      const float v = dt ? oacc1[r] : oacc0[r];
      ob[((size_t)b * SEQ + q0 + ql) * D_MODEL + dcol] = (f16)v;
    }
  }
}

// ---- sum the two kv-half partials into ctx ----
__global__ void k_add(const f16* __restrict__ a, const f16* __restrict__ b,
                      f16* __restrict__ o) {
  const int i = (blockIdx.x * 256 + threadIdx.x) * 8;
  const f16x8 x = *(const f16x8*)(a + i);
  const f16x8 y = *(const f16x8*)(b + i);
  f16x8 r;
#pragma unroll
  for (int j = 0; j < 8; ++j) r[j] = (f16)((float)x[j] + (float)y[j]);
  *(f16x8*)(o + i) = r;
}

extern "C" void kernel_launch(void* const* d_in, const int* in_sizes, int n_in,
                              void* d_out, int out_size, void* d_ws, size_t ws_size,
                              hipStream_t stream) {
  (void)in_sizes; (void)n_in; (void)out_size; (void)ws_size;
  const float* q  = (const float*)d_in[0];
  const float* k  = (const float*)d_in[1];
  const float* v  = (const float*)d_in[2];
  const float* Wq = (const float*)d_in[3];
  const float* bq = (const float*)d_in[4];
  const float* Wk = (const float*)d_in[5];
  const float* bk = (const float*)d_in[6];
  const float* Wv = (const float*)d_in[7];
  const float* bv = (const float*)d_in[8];
  const float* Wo = (const float*)d_in[9];
  const float* bo = (const float*)d_in[10];
  float* out = (float*)d_out;

  char* p = (char*)d_ws;
  const size_t SZ_X = (size_t)MTOT * D_MODEL * sizeof(f16);  // 8 MB
  f16* qb    = (f16*)p; p += 3 * SZ_X;
  f16* WqkvT = (f16*)p; p += 3 * (size_t)1024 * 1024 * sizeof(f16);
  f16* WoT   = (f16*)p; p += (size_t)1024 * 1024 * sizeof(f16);
  f16* QKVb  = (f16*)p; p += (size_t)MTOT * NQKV * sizeof(f16);
  f16* Vtb   = (f16*)p; p += SZ_X;
  f16* Opart = (f16*)p; p += 2 * SZ_X;
  f16* kb = qb + (size_t)MTOT * D_MODEL;
  f16* vb = kb + (size_t)MTOT * D_MODEL;
  f16* ctx = qb;  // reuse: qb dead after QKV GEMM

  k_cvt3<<<3 * MTOT * D_MODEL / 2048, 256, 0, stream>>>(q, k, v, qb);
  k_tw<<<dim3(32, 32, 4), dim3(32, 8), 0, stream>>>(Wq, Wk, Wv, Wo, WqkvT, WoT);
  k_gemm256<<<(MTOT / 256) * (NQKV / 256), 512, 0, stream>>>(
      qb, kb, vb, WqkvT, bq, bk, bv, QKVb, Vtb);
  k_attn<<<(SEQ / 128) * N_HEAD * BATCH * 2, 256, 0, stream>>>(QKVb, Vtb, Opart);
  k_add<<<MTOT * D_MODEL / 2048, 256, 0, stream>>>(
      Opart, Opart + (size_t)MTOT * D_MODEL, ctx);
  k_gemmO<<<(MTOT / 128) * (1024 / 128), 512, 0, stream>>>(ctx, WoT, bo, out);
}